// Round 1
// baseline (2050.015 us; speedup 1.0000x reference)
//
#include <hip/hip_runtime.h>
#include <cstdint>

#define CIN    512
#define COUT   32
#define IMH    56
#define IMW    56
#define NBATCH 32
#define BK     8       // cin chunk staged per iteration
#define RPB    8       // output rows per block
#define YTILES 7       // 56 / RPB
#define RPT    2       // rows per thread
#define NTHREADS 256

__global__ __launch_bounds__(NTHREADS, 2)
void fused_bn_relu_conv(const float* __restrict__ x,
                        const float* __restrict__ bn_w,
                        const float* __restrict__ bn_b,
                        const float* __restrict__ r_mean,
                        const float* __restrict__ r_var,
                        const float* __restrict__ cw,
                        float* __restrict__ out)
{
    __shared__ float s_scale[CIN];
    __shared__ float s_shift[CIN];
    __shared__ float s_in[BK][RPB + 2][IMW + 4];  // [8][10][60] — col 0 = input col -1
    __shared__ float s_w[BK][COUT][12];           // taps 0..8, padded to 12 for b128 reads

    const int tid = threadIdx.x;
    const int n   = blockIdx.x / YTILES;
    const int yt  = blockIdx.x % YTILES;
    const int y0  = yt * RPB;

    const int col  = tid & 63;        // 0..63; active when < 56
    const int rg   = tid >> 6;        // 0..3
    const int orow = rg * RPT;        // first output-row offset within block

    // Precompute BN scale/shift once: scale = gamma*rsqrt(var+eps), shift = beta - mean*scale
    for (int c = tid; c < CIN; c += NTHREADS) {
        float sc = bn_w[c] * rsqrtf(r_var[c] + 1e-5f);
        s_scale[c] = sc;
        s_shift[c] = bn_b[c] - r_mean[c] * sc;
    }
    __syncthreads();

    float acc[RPT][COUT];
    #pragma unroll
    for (int r = 0; r < RPT; ++r)
        #pragma unroll
        for (int co = 0; co < COUT; ++co) acc[r][co] = 0.f;

    const float* xn = x + (size_t)n * (CIN * IMH * IMW);

    for (int ck = 0; ck < CIN; ck += BK) {
        // Stage weights for this cin chunk: cw layout [cout][cin][3][3]
        for (int i = tid; i < BK * COUT * 9; i += NTHREADS) {
            int ci  = i / (COUT * 9);
            int rem = i - ci * (COUT * 9);
            int co  = rem / 9;
            int tap = rem - co * 9;
            s_w[ci][co][tap] = cw[((size_t)co * CIN + (ck + ci)) * 9 + tap];
        }
        // Stage inputs with fused BN+ReLU; zero-pad outside the image
        for (int i = tid; i < BK * (RPB + 2) * 58; i += NTHREADS) {
            int ci  = i / ((RPB + 2) * 58);
            int rem = i - ci * ((RPB + 2) * 58);
            int rr  = rem / 58;           // 0..9 -> input row y0-1+rr
            int cc  = rem - rr * 58;      // 0..57 -> input col cc-1
            int iy = y0 - 1 + rr;
            int ix = cc - 1;
            int c  = ck + ci;
            float v = 0.f;
            if (iy >= 0 && iy < IMH && ix >= 0 && ix < IMW) {
                v = fmaxf(xn[((size_t)c * IMH + iy) * IMW + ix] * s_scale[c] + s_shift[c], 0.f);
            }
            s_in[ci][rr][cc] = v;
        }
        __syncthreads();

        if (col < IMW) {
            for (int ci = 0; ci < BK; ++ci) {
                // 4 rows x 3 cols of staged input cover this thread's 2 output rows
                float vin[RPT + 2][3];
                #pragma unroll
                for (int r = 0; r < RPT + 2; ++r)
                    #pragma unroll
                    for (int dx = 0; dx < 3; ++dx)
                        vin[r][dx] = s_in[ci][orow + r][col + dx];

                #pragma unroll
                for (int co = 0; co < COUT; ++co) {
                    const float* wp = &s_w[ci][co][0];
                    float w0 = wp[0], w1 = wp[1], w2 = wp[2];
                    float w3 = wp[3], w4 = wp[4], w5 = wp[5];
                    float w6 = wp[6], w7 = wp[7], w8 = wp[8];
                    #pragma unroll
                    for (int r = 0; r < RPT; ++r) {
                        float a = acc[r][co];
                        a = fmaf(vin[r + 0][0], w0, a);
                        a = fmaf(vin[r + 0][1], w1, a);
                        a = fmaf(vin[r + 0][2], w2, a);
                        a = fmaf(vin[r + 1][0], w3, a);
                        a = fmaf(vin[r + 1][1], w4, a);
                        a = fmaf(vin[r + 1][2], w5, a);
                        a = fmaf(vin[r + 2][0], w6, a);
                        a = fmaf(vin[r + 2][1], w7, a);
                        a = fmaf(vin[r + 2][2], w8, a);
                        acc[r][co] = a;
                    }
                }
            }
        }
        __syncthreads();
    }

    if (col < IMW) {
        #pragma unroll
        for (int r = 0; r < RPT; ++r) {
            int oy = y0 + orow + r;
            #pragma unroll
            for (int co = 0; co < COUT; ++co) {
                out[(((size_t)n * COUT + co) * IMH + oy) * IMW + col] = acc[r][co];
            }
        }
    }
}

extern "C" void kernel_launch(void* const* d_in, const int* in_sizes, int n_in,
                              void* d_out, int out_size, void* d_ws, size_t ws_size,
                              hipStream_t stream) {
    // Input order: x_slice, out_map(unused), bn_weight, bn_bias, running_mean,
    //              running_var, conv_weight, write_offset(unused — output IS the slice)
    const float* x      = (const float*)d_in[0];
    const float* bn_w   = (const float*)d_in[2];
    const float* bn_b   = (const float*)d_in[3];
    const float* r_mean = (const float*)d_in[4];
    const float* r_var  = (const float*)d_in[5];
    const float* cw     = (const float*)d_in[6];
    float* out = (float*)d_out;

    fused_bn_relu_conv<<<dim3(NBATCH * YTILES), dim3(NTHREADS), 0, stream>>>(
        x, bn_w, bn_b, r_mean, r_var, cw, out);
}

// Round 2
// 669.182 us; speedup vs baseline: 3.0635x; 3.0635x over previous
//
#include <hip/hip_runtime.h>
#include <cstdint>

#define CIN   512
#define COUT  32
#define IMH   56
#define IMW   56
#define NB    32
#define G     4          // cin groups (blocks doing partial sums)
#define RPB   8          // output rows per block
#define YT    7          // 56 / RPB
#define XSTR  40         // padded k-stride in s_x (elements); 80B -> conflict-free
#define NTH   256

typedef __attribute__((ext_vector_type(8))) short v8s;   // 8 bf16 = 4 VGPRs
typedef __attribute__((ext_vector_type(4))) float v4f;   // C/D frag

__device__ __forceinline__ unsigned short f2bf(float f) {
    unsigned u = __builtin_bit_cast(unsigned, f);
    u += 0x7FFFu + ((u >> 16) & 1u);          // round-to-nearest-even
    return (unsigned short)(u >> 16);
}

// ---------------------------------------------------------------------------
// Weight transform: cw[cout][cin][3][3] fp32 -> w2 bf16 in MFMA A-fragment
// lane order: w2[((c32*9 + tap)*2 + mt)*64 + lane][8]
//   A[m = mt*16 + (lane&15)][k = c32*32 + (lane>>4)*8 + j]
// ---------------------------------------------------------------------------
__global__ void wtransform(const float* __restrict__ cw,
                           unsigned short* __restrict__ w2) {
    int idx = blockIdx.x * blockDim.x + threadIdx.x;
    if (idx >= 16 * 9 * 2 * 64 * 8) return;
    int j    = idx & 7;
    int lane = (idx >> 3) & 63;
    int mt   = (idx >> 9) & 1;
    int tmp  = idx >> 10;            // 0..143
    int tap  = tmp % 9;
    int c32  = tmp / 9;              // global 32-channel chunk 0..15
    int m = mt * 16 + (lane & 15);
    int k = c32 * 32 + (lane >> 4) * 8 + j;
    w2[idx] = f2bf(cw[((size_t)m * CIN + k) * 9 + tap]);
}

// ---------------------------------------------------------------------------
// Fused BN+ReLU+3x3 conv via tap-decomposed implicit GEMM, bf16 MFMA.
// Block: (n, ytile, cingroup). 4 waves; each wave 7 pixel-tiles of 16.
// ---------------------------------------------------------------------------
__global__ __launch_bounds__(NTH, 2)
void conv_mfma(const float* __restrict__ x,
               const float* __restrict__ bn_w, const float* __restrict__ bn_b,
               const float* __restrict__ r_mean, const float* __restrict__ r_var,
               const unsigned short* __restrict__ w2,
               float* __restrict__ out)
{
    __shared__ unsigned short s_x[10 * 58 * XSTR];   // 46400 B, [row][col][k<=31 +pad]
    __shared__ unsigned short s_w[9 * 2 * 64 * 8];   // 18432 B, fragment-linear

    const int tid  = threadIdx.x;
    const int lane = tid & 63;
    const int wv   = tid >> 6;            // wave 0..3
    const int yt   = blockIdx.x >> 2;     // 0..6
    const int g    = blockIdx.x & 3;      // cin group 0..3
    const int n    = blockIdx.y;
    const int y0   = yt * RPB;
    const int c2   = tid & 15;            // staging channel-pair id (invariant)

    // Per-tile B-fragment base addresses (lane-constant across chunks) + acc
    v4f acc[7][2];
    int b_base[7];
    const v4f zero4 = {0.f, 0.f, 0.f, 0.f};
    #pragma unroll
    for (int i = 0; i < 7; ++i) {
        int p  = (wv * 7 + i) * 16 + (lane & 15);   // pixel in 448-px row tile
        int py = p / 56, px = p % 56;
        b_base[i] = (py * 58 + px) * XSTR + (lane >> 4) * 8;
        acc[i][0] = zero4;
        acc[i][1] = zero4;
    }

    // Pre-zero halo columns t=0 and t=57 (conv zero-padding of relu_out)
    for (int i = tid; i < 400; i += NTH) {
        int kq = i % 20;                 // u32 slot: k = kq*2 (covers k 0..39)
        int r  = i / 20;                 // 0..19
        int t  = (r & 1) ? 57 : 0;
        int y  = r >> 1;                 // 0..9
        *(unsigned*)&s_x[(y * 58 + t) * XSTR + kq * 2] = 0u;
    }

    const float* xn = x + (size_t)n * CIN * 3136;

    for (int cc = 0; cc < 4; ++cc) {
        __syncthreads();                         // prev compute done / prezero visible
        const int gc = g * 4 + cc;               // global chunk 0..15
        const int ca = gc * 32 + c2 * 2;         // this thread's staging channels

        // --- stage weights: linear 16B copy (coalesced, conflict-free) ---
        const uint4* wsrc = (const uint4*)(w2 + (size_t)gc * 9216);
        for (int i = tid; i < 1152; i += NTH)
            ((uint4*)s_w)[i] = wsrc[i];

        // --- per-thread BN constants for its channel pair ---
        float sa  = bn_w[ca]     * rsqrtf(r_var[ca]     + 1e-5f);
        float sha = bn_b[ca]     - r_mean[ca]     * sa;
        float sb  = bn_w[ca + 1] * rsqrtf(r_var[ca + 1] + 1e-5f);
        float shb = bn_b[ca + 1] - r_mean[ca + 1] * sb;

        // --- stage input: BN+ReLU+bf16, k-innermost; slots y(10) x xg(14) x c2(16)
        for (int s = tid; s < 2240; s += NTH) {
            int rest = s >> 4;               // (s & 15) == c2 always
            int xg = rest % 14;
            int y  = rest / 14;              // 0..9
            int iy = y0 - 1 + y;
            unsigned u[4] = {0u, 0u, 0u, 0u};
            if (iy >= 0 && iy < IMH) {
                const float* pa = xn + (size_t)ca * 3136 + iy * 56 + xg * 4;
                float4 va = *(const float4*)pa;
                float4 vb = *(const float4*)(pa + 3136);
                float a0 = fmaxf(fmaf(va.x, sa, sha), 0.f);
                float a1 = fmaxf(fmaf(va.y, sa, sha), 0.f);
                float a2 = fmaxf(fmaf(va.z, sa, sha), 0.f);
                float a3 = fmaxf(fmaf(va.w, sa, sha), 0.f);
                float b0 = fmaxf(fmaf(vb.x, sb, shb), 0.f);
                float b1 = fmaxf(fmaf(vb.y, sb, shb), 0.f);
                float b2 = fmaxf(fmaf(vb.z, sb, shb), 0.f);
                float b3 = fmaxf(fmaf(vb.w, sb, shb), 0.f);
                u[0] = (unsigned)f2bf(a0) | ((unsigned)f2bf(b0) << 16);
                u[1] = (unsigned)f2bf(a1) | ((unsigned)f2bf(b1) << 16);
                u[2] = (unsigned)f2bf(a2) | ((unsigned)f2bf(b2) << 16);
                u[3] = (unsigned)f2bf(a3) | ((unsigned)f2bf(b3) << 16);
            }
            int base = (y * 58 + xg * 4 + 1) * XSTR + c2 * 2;
            #pragma unroll
            for (int e = 0; e < 4; ++e)
                *(unsigned*)&s_x[base + e * XSTR] = u[e];
        }
        __syncthreads();

        // --- compute: 9 taps x 7 tiles x 2 m-tiles ---
        #pragma unroll
        for (int tap = 0; tap < 9; ++tap) {
            const int ky = tap / 3, kx = tap % 3;
            v8s a0 = *(const v8s*)&s_w[((tap * 2 + 0) * 64 + lane) * 8];
            v8s a1 = *(const v8s*)&s_w[((tap * 2 + 1) * 64 + lane) * 8];
            const int toff = (ky * 58 + kx) * XSTR;
            #pragma unroll
            for (int i = 0; i < 7; ++i) {
                v8s b = *(const v8s*)&s_x[b_base[i] + toff];
                acc[i][0] = __builtin_amdgcn_mfma_f32_16x16x32_bf16(a0, b, acc[i][0], 0, 0, 0);
                acc[i][1] = __builtin_amdgcn_mfma_f32_16x16x32_bf16(a1, b, acc[i][1], 0, 0, 0);
            }
        }
    }

    // --- epilogue: partial-sum accumulate into zeroed d_out ---
    const int prow = (lane >> 4) * 4;
    #pragma unroll
    for (int i = 0; i < 7; ++i) {
        int p = (wv * 7 + i) * 16 + (lane & 15);
        size_t o0 = (size_t)n * COUT * 3136 + y0 * 56 + p;
        #pragma unroll
        for (int mt = 0; mt < 2; ++mt) {
            #pragma unroll
            for (int r = 0; r < 4; ++r) {
                int cout = mt * 16 + prow + r;
                atomicAdd(&out[o0 + (size_t)cout * 3136], acc[i][mt][r]);
            }
        }
    }
}

extern "C" void kernel_launch(void* const* d_in, const int* in_sizes, int n_in,
                              void* d_out, int out_size, void* d_ws, size_t ws_size,
                              hipStream_t stream) {
    const float* x      = (const float*)d_in[0];
    const float* bn_w   = (const float*)d_in[2];
    const float* bn_b   = (const float*)d_in[3];
    const float* r_mean = (const float*)d_in[4];
    const float* r_var  = (const float*)d_in[5];
    const float* cw     = (const float*)d_in[6];
    float* out = (float*)d_out;
    unsigned short* w2 = (unsigned short*)d_ws;   // 294912 B

    // d_out is poisoned 0xAA each call -> zero it (atomics accumulate into it)
    hipMemsetAsync(d_out, 0, (size_t)out_size * sizeof(float), stream);

    wtransform<<<dim3(576), dim3(256), 0, stream>>>(cw, w2);

    conv_mfma<<<dim3(YT * G, NB), dim3(NTH), 0, stream>>>(
        x, bn_w, bn_b, r_mean, r_var, w2, out);
}

// Round 3
// 616.656 us; speedup vs baseline: 3.3244x; 1.0852x over previous
//
#include <hip/hip_runtime.h>
#include <cstdint>

#define CIN    512
#define COUT   32
#define IMH    56
#define IMW    56
#define NB     32
#define YT     7         // 8-row tiles
#define RPB    8
#define XSTR   40        // padded k-stride (elements); 80 B
#define NTH    256
#define CHUNKS 16        // 512 / 32
#define SLOTS  2240      // 10 rows x 14 col-groups x 16 channel-pairs
#define SPT    9         // ceil(2240/256)

typedef __attribute__((ext_vector_type(8))) short v8s;   // 8 bf16 = 4 VGPRs
typedef __attribute__((ext_vector_type(4))) float v4f;

__device__ __forceinline__ unsigned short f2bf(float f) {
    unsigned u = __builtin_bit_cast(unsigned, f);
    u += 0x7FFFu + ((u >> 16) & 1u);          // round-to-nearest-even
    return (unsigned short)(u >> 16);
}

// ---------------------------------------------------------------------------
// Weight transform: cw[cout][cin][3][3] fp32 -> w2 bf16 in MFMA A-frag order:
// w2[(((c32*9 + tap)*2 + mt)*64 + lane)*8 + j] = W[m=mt*16+(lane&15)][k=c32*32+(lane>>4)*8+j][tap]
// ---------------------------------------------------------------------------
__global__ void wtransform(const float* __restrict__ cw,
                           unsigned short* __restrict__ w2) {
    int idx = blockIdx.x * blockDim.x + threadIdx.x;
    if (idx >= CHUNKS * 9 * 2 * 64 * 8) return;
    int j    = idx & 7;
    int lane = (idx >> 3) & 63;
    int mt   = (idx >> 9) & 1;
    int tmp  = idx >> 10;
    int tap  = tmp % 9;
    int c32  = tmp / 9;
    int m = mt * 16 + (lane & 15);
    int k = c32 * 32 + (lane >> 4) * 8 + j;
    w2[idx] = f2bf(cw[((size_t)m * CIN + k) * 9 + tap]);
}

// ---------------------------------------------------------------------------
// Fused BN+ReLU+3x3 conv, tap-decomposed implicit GEMM, full-K per block,
// software-pipelined: dbuf LDS input; weights straight from L2 to registers.
// Grid (7, 32): yt x n. 4 waves; wave w owns pixel-tiles w*7..w*7+6, both mt.
// ---------------------------------------------------------------------------
__global__ __launch_bounds__(NTH, 1)
void conv_mfma(const float* __restrict__ x,
               const float* __restrict__ bn_w, const float* __restrict__ bn_b,
               const float* __restrict__ r_mean, const float* __restrict__ r_var,
               const unsigned short* __restrict__ w2,
               float* __restrict__ out)
{
    __shared__ unsigned short s_x[2][10 * 58 * XSTR];  // 2 x 46400 B
    __shared__ float s_scale[CIN];
    __shared__ float s_shift[CIN];

    const int tid  = threadIdx.x;
    const int lane = tid & 63;
    const int wv   = tid >> 6;
    const int yt   = blockIdx.x;
    const int n    = blockIdx.y;
    const int y0   = yt * RPB;
    const int c2   = tid & 15;           // staging channel-pair (tid-invariant)

    // BN scale/shift tables (512 ch), once
    for (int c = tid; c < CIN; c += NTH) {
        float sc = bn_w[c] * rsqrtf(r_var[c] + 1e-5f);
        s_scale[c] = sc;
        s_shift[c] = bn_b[c] - r_mean[c] * sc;
    }

    // Pre-zero halo columns (t=0,57) in BOTH buffers; never rewritten
    for (int i = tid; i < 800; i += NTH) {
        int b  = i >= 400;
        int ii = i - b * 400;
        int kq = ii % 20;
        int r  = ii / 20;
        int t  = (r & 1) ? 57 : 0;
        int y  = r >> 1;
        *(unsigned*)&s_x[b][(y * 58 + t) * XSTR + kq * 2] = 0u;
    }

    // Per-thread staging slot tables (chunk-invariant)
    int    lbase[SPT];
    size_t goff[SPT];
    bool   active[SPT], vrow[SPT];
    #pragma unroll
    for (int j = 0; j < SPT; ++j) {
        int slot = tid + j * NTH;
        active[j] = (slot < SLOTS);
        int rest = slot >> 4;
        int xg = rest % 14;
        int y  = rest / 14;               // 0..9
        int iy = y0 - 1 + y;
        vrow[j]  = active[j] && (iy >= 0) && (iy < IMH);
        lbase[j] = (y * 58 + xg * 4 + 1) * XSTR + c2 * 2;
        goff[j]  = (size_t)(c2 * 2) * 3136 + (size_t)(vrow[j] ? iy : 0) * 56 + xg * 4;
    }

    // Accumulators + B-fragment bases (7 tiles x 2 mt per wave)
    v4f acc[7][2];
    int b_base[7];
    const v4f zero4 = {0.f, 0.f, 0.f, 0.f};
    #pragma unroll
    for (int i = 0; i < 7; ++i) {
        int p  = (wv * 7 + i) * 16 + (lane & 15);
        int py = p / 56, px = p % 56;
        b_base[i] = (py * 58 + px) * XSTR + (lane >> 4) * 8;
        acc[i][0] = zero4;
        acc[i][1] = zero4;
    }

    const float* xn = x + (size_t)n * CIN * 3136;

    // --- prefetch chunk 0 input into registers ---
    float4 va[SPT], vb[SPT];
    #pragma unroll
    for (int j = 0; j < SPT; ++j) {
        if (vrow[j]) {
            const float* p = xn + goff[j];
            va[j] = *(const float4*)p;
            vb[j] = *(const float4*)(p + 3136);
        }
    }

    for (int gc = 0; gc < CHUNKS; ++gc) {
        // 1) weight A-frags for chunk gc from L2 (oldest vmem this iter)
        v8s a0[9], a1[9];
        const v8s* wp = (const v8s*)(w2 + (size_t)gc * 9216);
        #pragma unroll
        for (int tap = 0; tap < 9; ++tap) {
            a0[tap] = wp[tap * 128 + lane];
            a1[tap] = wp[tap * 128 + 64 + lane];
        }

        // 2) pack chunk gc (waits input loads of gc only; weights stay in flight)
        const int ca = gc * 32 + c2 * 2;
        const float sa = s_scale[ca],     sha = s_shift[ca];
        const float sb = s_scale[ca + 1], shb = s_shift[ca + 1];
        unsigned short* bptr = s_x[gc & 1];
        #pragma unroll
        for (int j = 0; j < SPT; ++j) {
            if (!active[j]) continue;
            unsigned u[4] = {0u, 0u, 0u, 0u};
            if (vrow[j]) {
                float a0f = fmaxf(fmaf(va[j].x, sa, sha), 0.f);
                float a1f = fmaxf(fmaf(va[j].y, sa, sha), 0.f);
                float a2f = fmaxf(fmaf(va[j].z, sa, sha), 0.f);
                float a3f = fmaxf(fmaf(va[j].w, sa, sha), 0.f);
                float b0f = fmaxf(fmaf(vb[j].x, sb, shb), 0.f);
                float b1f = fmaxf(fmaf(vb[j].y, sb, shb), 0.f);
                float b2f = fmaxf(fmaf(vb[j].z, sb, shb), 0.f);
                float b3f = fmaxf(fmaf(vb[j].w, sb, shb), 0.f);
                u[0] = (unsigned)f2bf(a0f) | ((unsigned)f2bf(b0f) << 16);
                u[1] = (unsigned)f2bf(a1f) | ((unsigned)f2bf(b1f) << 16);
                u[2] = (unsigned)f2bf(a2f) | ((unsigned)f2bf(b2f) << 16);
                u[3] = (unsigned)f2bf(a3f) | ((unsigned)f2bf(b3f) << 16);
            }
            int base = lbase[j];
            #pragma unroll
            for (int e = 0; e < 4; ++e)
                *(unsigned*)&bptr[base + e * XSTR] = u[e];
        }

        // 3) prefetch chunk gc+1 input (newest vmem; in flight across barrier+MFMA)
        if (gc < CHUNKS - 1) {
            const float* bnext = xn + (size_t)(gc + 1) * 32 * 3136;
            #pragma unroll
            for (int j = 0; j < SPT; ++j) {
                if (vrow[j]) {
                    const float* p = bnext + goff[j];
                    va[j] = *(const float4*)p;
                    vb[j] = *(const float4*)(p + 3136);
                }
            }
        }

        // 4) one barrier per chunk (dbuf makes it WAR-safe)
        __syncthreads();

        // 5) MFMA chunk gc (waits weight loads only; prefetch stays outstanding)
        #pragma unroll
        for (int tap = 0; tap < 9; ++tap) {
            const int toff = ((tap / 3) * 58 + (tap % 3)) * XSTR;
            #pragma unroll
            for (int i = 0; i < 7; ++i) {
                v8s b = *(const v8s*)&bptr[b_base[i] + toff];
                acc[i][0] = __builtin_amdgcn_mfma_f32_16x16x32_bf16(a0[tap], b, acc[i][0], 0, 0, 0);
                acc[i][1] = __builtin_amdgcn_mfma_f32_16x16x32_bf16(a1[tap], b, acc[i][1], 0, 0, 0);
            }
        }
    }

    // --- epilogue: direct stores (each output element owned by one thread) ---
    const int prow = (lane >> 4) * 4;
    #pragma unroll
    for (int i = 0; i < 7; ++i) {
        int p = (wv * 7 + i) * 16 + (lane & 15);
        size_t o0 = (size_t)n * COUT * 3136 + (size_t)y0 * 56 + p;
        #pragma unroll
        for (int mt = 0; mt < 2; ++mt) {
            #pragma unroll
            for (int r = 0; r < 4; ++r) {
                int cout = mt * 16 + prow + r;
                out[o0 + (size_t)cout * 3136] = acc[i][mt][r];
            }
        }
    }
}

extern "C" void kernel_launch(void* const* d_in, const int* in_sizes, int n_in,
                              void* d_out, int out_size, void* d_ws, size_t ws_size,
                              hipStream_t stream) {
    const float* x      = (const float*)d_in[0];
    const float* bn_w   = (const float*)d_in[2];
    const float* bn_b   = (const float*)d_in[3];
    const float* r_mean = (const float*)d_in[4];
    const float* r_var  = (const float*)d_in[5];
    const float* cw     = (const float*)d_in[6];
    float* out = (float*)d_out;
    unsigned short* w2 = (unsigned short*)d_ws;   // 294912 B used

    wtransform<<<dim3(576), dim3(256), 0, stream>>>(cw, w2);

    conv_mfma<<<dim3(YT, NB), dim3(NTH), 0, stream>>>(
        x, bn_w, bn_b, r_mean, r_var, w2, out);
}